// Round 17
// baseline (309.829 us; speedup 1.0000x reference)
//
#include <hip/hip_runtime.h>

#define N_GRAPHS 100000
#define NTYPES 8
#define MAXD 128
#define FEAT 256
#define NB 2            // two 16-graph halves per wave -> 32 graphs/wave
#define GPW (16 * NB)
#define ALDA 136        // As row stride, shorts (272B); 32 rows = 8704B/wave
#define ELDA 68         // Ep row stride, floats (272B); 16 rows = 4352B/wave

typedef __attribute__((ext_vector_type(8))) short short8;
typedef __attribute__((ext_vector_type(4))) float f32x4;
typedef __attribute__((ext_vector_type(4))) unsigned uint4v;

constexpr int KSN[NTYPES]  = {1, 1, 2, 4, 2, 1, 1, 4};
constexpr int DIMS[NTYPES] = {16, 32, 64, 128, 64, 32, 16, 128};

__device__ __forceinline__ unsigned f2bf_u(float f) {
    unsigned u = __builtin_bit_cast(unsigned, f);
    return (u + 0x7fffu + ((u >> 16) & 1u)) >> 16;   // round-to-nearest-even
}
__device__ __forceinline__ unsigned cvt2(float lo, float hi) {
    return f2bf_u(lo) | (f2bf_u(hi) << 16);
}
__device__ __forceinline__ short8 cvt8(f32x4 a, f32x4 b) {
    uint4v u;
    u.x = cvt2(a.x, a.y); u.y = cvt2(a.z, a.w);
    u.z = cvt2(b.x, b.y); u.w = cvt2(b.z, b.w);
    return __builtin_bit_cast(short8, u);
}

// --- W -> bf16 fragment prepack. wp[(((t*16 + ct)*4 + ks)*4 + cgrp)*16 + c16]
//     = W[t][ct*16 + c16][ks*32 + cgrp*8 .. +7], zero-masked at k >= dim. 512 KB.
__global__ __launch_bounds__(256)
void prepack_w(const float* __restrict__ W, short8* __restrict__ wp)
{
    const int idx  = blockIdx.x * 256 + threadIdx.x;   // 32768
    const int c16  = idx & 15;
    const int cgrp = (idx >> 4) & 3;
    const int ks   = (idx >> 6) & 3;
    const int ct   = (idx >> 8) & 15;
    const int t    = (idx >> 12) & 7;
    const int col  = ct * 16 + c16;
    const int k    = ks * 32 + cgrp * 8;
    const int dim  = 16 << ((0x30123210u >> (4 * t)) & 0xf);
    const float* src = W + ((size_t)t * FEAT + col) * MAXD + k;
    f32x4 a = *(const f32x4*)src;
    f32x4 b = *(const f32x4*)(src + 4);
    #pragma unroll
    for (int j = 0; j < 4; ++j) {
        if (k + j     >= dim) a[j] = 0.f;
        if (k + 4 + j >= dim) b[j] = 0.f;
    }
    wp[idx] = cvt8(a, b);
}

// One type for one wave's 32 graphs. No barriers (wave-private As/Ep, in-order
// DS pipe). THE LEVER THIS ROUND: wf fragments (wp) are loaded ONCE per ct4
// and reused for BOTH 16-graph halves -> wp L2 traffic halves (8KB/graph ->
// 4KB/graph); each wf load feeds 2 MFMA chains.
template<int T, bool PRE>
__device__ __forceinline__ void do_type(const float* __restrict__ x,
                                        const short8* __restrict__ wp,
                                        const float* __restrict__ W,
                                        const float* __restrict__ bias_g,
                                        float* __restrict__ out,
                                        unsigned short* __restrict__ as_,
                                        float* __restrict__ ep,
                                        int g0, int lane, int cgrp, int c16)
{
    constexpr int KS = KSN[T];

    // A fragments for both halves: row = b*16 + c16, k = ks*32 + cgrp*8
    short8 a[NB][KS];
    #pragma unroll
    for (int b = 0; b < NB; ++b)
        #pragma unroll
        for (int ks = 0; ks < KS; ++ks)
            a[b][ks] = *(const short8*)&as_[(b * 16 + c16) * ALDA + ks * 32 + cgrp * 8];

    // 4 groups of 4 feature-tiles; wf held in regs across both halves
    #pragma unroll
    for (int ct4 = 0; ct4 < 4; ++ct4) {
        short8 wf4[4][KS];
        #pragma unroll
        for (int c = 0; c < 4; ++c) {
            const int ct = ct4 * 4 + c;
            if constexpr (PRE) {
                #pragma unroll
                for (int ks = 0; ks < KS; ++ks)
                    wf4[c][ks] = wp[(((T * 16 + ct) * 4 + ks) * 4 + cgrp) * 16 + c16];
            } else {
                constexpr int DIM = DIMS[T];
                #pragma unroll
                for (int ks = 0; ks < KS; ++ks) {
                    const int k = ks * 32 + cgrp * 8;
                    const float* wfp = W + ((size_t)T * FEAT + ct * 16 + c16) * MAXD + k;
                    f32x4 wa = *(const f32x4*)wfp;
                    f32x4 wb = *(const f32x4*)(wfp + 4);
                    #pragma unroll
                    for (int j = 0; j < 4; ++j) {
                        if (k + j     >= DIM) wa[j] = 0.f;
                        if (k + 4 + j >= DIM) wb[j] = 0.f;
                    }
                    wf4[c][ks] = cvt8(wa, wb);
                }
            }
        }
        #pragma unroll
        for (int b = 0; b < NB; ++b) {
            #pragma unroll
            for (int c = 0; c < 4; ++c) {
                f32x4 acc = {0.f, 0.f, 0.f, 0.f};
                #pragma unroll
                for (int ks = 0; ks < KS; ++ks)
                    acc = __builtin_amdgcn_mfma_f32_16x16x32_bf16(a[b][ks], wf4[c][ks], acc, 0, 0, 0);
                // D: row (graph) = cgrp*4 + r, col (feat) = ct*16 + c16  [m89]
                #pragma unroll
                for (int r = 0; r < 4; ++r)
                    ep[(cgrp * 4 + r) * ELDA + c * 16 + c16] = acc[r];
            }
            // flush half b: 16 graphs x 64 feats (in-order DS pipe: writes
            // above complete before these reads; reads before next b's writes)
            #pragma unroll
            for (int i = 0; i < 4; ++i) {
                const int row   = i * 4 + (lane >> 4);
                const int coldw = (lane & 15) * 4;
                f32x4 v  = *(const f32x4*)&ep[row * ELDA + coldw];
                f32x4 b4 = *(const f32x4*)&bias_g[T * FEAT + ct4 * 64 + coldw];
                f32x4 res;
                #pragma unroll
                for (int r = 0; r < 4; ++r) res[r] = v[r] + b4[r];
                __builtin_nontemporal_store(res,
                    (f32x4*)&out[(((size_t)(g0 + b * 16 + row)) * NTYPES + T) * FEAT + ct4 * 64 + coldw]);
            }
        }
    }

    // stage next type's A (32 rows) into As; a-frags already in regs so the
    // in-order DS pipe makes this safe without any barrier
    if constexpr (T + 1 < NTYPES) {
        constexpr int KSn  = KSN[T + 1];
        constexpr int SPRn = KSn * 4;           // 8-float segments per row
        #pragma unroll
        for (int p = 0; p < 2 * KSn; ++p) {     // 32 rows x SPRn / 64 lanes
            const int idx = p * 64 + lane;
            const int row = idx / SPRn, s8 = idx % SPRn;
            const float* rp = x + (((size_t)(g0 + row)) * NTYPES + (T + 1)) * MAXD + s8 * 8;
            f32x4 v0 = __builtin_nontemporal_load((const f32x4*)rp);
            f32x4 v1 = __builtin_nontemporal_load((const f32x4*)rp + 1);
            *(short8*)&as_[row * ALDA + s8 * 8] = cvt8(v0, v1);
        }
        do_type<T + 1, PRE>(x, wp, W, bias_g, out, as_, ep, g0, lane, cgrp, c16);
    }
}

// 3125 wave-tiles of 32 graphs (100000 = 3125*32, zero masking). 4 independent
// waves per block, zero __syncthreads. LDS = 4 x (8704 + 4352) = 52.2 KB ->
// 3 blocks/CU, 12 waves/CU (same as R12; the only lever is wp reuse).
template<bool PRE>
__global__ __launch_bounds__(256, 3)
void node_enc(const float* __restrict__ x, const short8* __restrict__ wp,
              const float* __restrict__ W, const float* __restrict__ bias_g,
              float* __restrict__ out)
{
    __shared__ __align__(16) unsigned short As[4][GPW * ALDA];  // 4 x 8704 B
    __shared__ __align__(16) float          Ep[4][16 * ELDA];   // 4 x 4352 B
    const int tid  = threadIdx.x;
    const int lane = tid & 63;
    const int wave = tid >> 6;
    const int cgrp = lane >> 4;
    const int c16  = lane & 15;
    const int w    = blockIdx.x * 4 + wave;
    if (w >= N_GRAPHS / GPW) return;   // whole-wave exit (last block only)
    const int g0   = w * GPW;

    unsigned short* as_ = As[wave];
    // prologue: stage T=0 (KS=1): 32 rows x 4 segs = 2 passes
    #pragma unroll
    for (int p = 0; p < 2; ++p) {
        const int idx = p * 64 + lane;
        const int row = idx >> 2, s8 = idx & 3;
        const float* rp = x + (((size_t)(g0 + row)) * NTYPES + 0) * MAXD + s8 * 8;
        f32x4 v0 = __builtin_nontemporal_load((const f32x4*)rp);
        f32x4 v1 = __builtin_nontemporal_load((const f32x4*)rp + 1);
        *(short8*)&as_[row * ALDA + s8 * 8] = cvt8(v0, v1);
    }

    do_type<0, PRE>(x, wp, W, bias_g, out, as_, Ep[wave], g0, lane, cgrp, c16);
}

extern "C" void kernel_launch(void* const* d_in, const int* in_sizes, int n_in,
                              void* d_out, int out_size, void* d_ws, size_t ws_size,
                              hipStream_t stream)
{
    const float* x = (const float*)d_in[0];
    const float* W = (const float*)d_in[1];
    const float* b = (const float*)d_in[2];
    float* out = (float*)d_out;

    const int grid = (N_GRAPHS / GPW + 3) / 4;                // 782
    const size_t wp_bytes = (size_t)32768 * sizeof(short8);   // 512 KB

    if (ws_size >= wp_bytes) {
        short8* wp = (short8*)d_ws;
        prepack_w<<<128, 256, 0, stream>>>(W, wp);
        node_enc<true><<<grid, 256, 0, stream>>>(x, wp, W, b, out);
    } else {
        node_enc<false><<<grid, 256, 0, stream>>>(x, nullptr, W, b, out);
    }
}

// Round 18
// 299.478 us; speedup vs baseline: 1.0346x; 1.0346x over previous
//
#include <hip/hip_runtime.h>

#define N_GRAPHS 100000
#define NTYPES 8
#define MAXD 128
#define FEAT 256
#define ALDA 136   // As row stride, shorts (272B)
#define ELDA 68    // Ep row stride, floats (272B)
#define ORDER_PACK 0x73426510u   // types in class order: 0,1,5,6 | 2,4 | 3,7
#define KSN_PACK   0x41124211u   // KS per TYPE id: {1,1,2,4,2,1,1,4}

typedef __attribute__((ext_vector_type(8))) short short8;
typedef __attribute__((ext_vector_type(4))) float f32x4;
typedef __attribute__((ext_vector_type(4))) unsigned uint4v;

__device__ __forceinline__ unsigned f2bf_u(float f) {
    unsigned u = __builtin_bit_cast(unsigned, f);
    return (u + 0x7fffu + ((u >> 16) & 1u)) >> 16;   // round-to-nearest-even
}
__device__ __forceinline__ unsigned cvt2(float lo, float hi) {
    return f2bf_u(lo) | (f2bf_u(hi) << 16);
}
__device__ __forceinline__ short8 cvt8(f32x4 a, f32x4 b) {
    uint4v u;
    u.x = cvt2(a.x, a.y); u.y = cvt2(a.z, a.w);
    u.z = cvt2(b.x, b.y); u.w = cvt2(b.z, b.w);
    return __builtin_bit_cast(short8, u);
}

// --- W -> bf16 fragment prepack. wp[(((t*16 + ct)*4 + ks)*4 + cgrp)*16 + c16]
//     = W[t][ct*16 + c16][ks*32 + cgrp*8 .. +7], zero-masked at k >= dim. 512 KB.
__global__ __launch_bounds__(256)
void prepack_w(const float* __restrict__ W, short8* __restrict__ wp)
{
    const int idx  = blockIdx.x * 256 + threadIdx.x;   // 32768
    const int c16  = idx & 15;
    const int cgrp = (idx >> 4) & 3;
    const int ks   = (idx >> 6) & 3;
    const int ct   = (idx >> 8) & 15;
    const int t    = (idx >> 12) & 7;
    const int col  = ct * 16 + c16;
    const int k    = ks * 32 + cgrp * 8;
    const int dim  = 16 << ((0x30123210u >> (4 * t)) & 0xf);
    const float* src = W + ((size_t)t * FEAT + col) * MAXD + k;
    f32x4 a = *(const f32x4*)src;
    f32x4 b = *(const f32x4*)(src + 4);
    #pragma unroll
    for (int j = 0; j < 4; ++j) {
        if (k + j     >= dim) a[j] = 0.f;
        if (k + 4 + j >= dim) b[j] = 0.f;
    }
    wp[idx] = cvt8(a, b);
}

// Issue 16 rows x (KSN_*32) floats of type TN as nt loads into pv (static idx).
template<int KSN_>
__device__ __forceinline__ void stage_issue(const float* __restrict__ x, int TN,
                                            int g0, int lane, f32x4* __restrict__ pv)
{
    constexpr int SPR = KSN_ * 4;    // 8-float segments per row
    #pragma unroll
    for (int p = 0; p < KSN_; ++p) {
        const int idx = p * 64 + lane;
        const int row = idx / SPR, s8 = idx % SPR;
        const float* rp = x + (((size_t)(g0 + row)) * NTYPES + TN) * MAXD + s8 * 8;
        pv[2 * p]     = __builtin_nontemporal_load((const f32x4*)rp);
        pv[2 * p + 1] = __builtin_nontemporal_load((const f32x4*)rp + 1);
    }
}
// cvt + ds_write the issued rows into As (after compute; vmcnt waits here).
template<int KSN_>
__device__ __forceinline__ void stage_write(unsigned short* __restrict__ as_,
                                            int lane, const f32x4* __restrict__ pv)
{
    constexpr int SPR = KSN_ * 4;
    #pragma unroll
    for (int p = 0; p < KSN_; ++p) {
        const int idx = p * 64 + lane;
        const int row = idx / SPR, s8 = idx % SPR;
        *(short8*)&as_[row * ALDA + s8 * 8] = cvt8(pv[2 * p], pv[2 * p + 1]);
    }
}

// One KS class: runtime loop over its types (NOT unrolled -> 3 compact bodies
// total instead of 8 -> kernel fits I-cache; executed work identical to R12).
template<int KS, bool PRE>
__device__ __forceinline__ void do_class(int ib, int ie,
                                         const float* __restrict__ x,
                                         const short8* __restrict__ wp,
                                         const float* __restrict__ W,
                                         const float* __restrict__ bias_g,
                                         float* __restrict__ out,
                                         unsigned short* __restrict__ as_,
                                         float* __restrict__ ep,
                                         int g0, int lane, int cgrp, int c16)
{
    #pragma unroll 1
    for (int i = ib; i < ie; ++i) {
        const int T = (ORDER_PACK >> (4 * i)) & 15;

        // A fragments of T: row = graph = c16, k = ks*32 + cgrp*8 (As free after)
        short8 a[KS];
        #pragma unroll
        for (int ks = 0; ks < KS; ++ks)
            a[ks] = *(const short8*)&as_[c16 * ALDA + ks * 32 + cgrp * 8];

        // T14 split: ISSUE next type's x loads now; LDS-write after compute
        f32x4 pv[8];
        int KSn = 0, TN = 0;
        if (i + 1 < NTYPES) {
            TN  = (ORDER_PACK >> (4 * (i + 1))) & 15;
            KSn = (KSN_PACK >> (4 * TN)) & 15;
            if (KSn == 1)      stage_issue<1>(x, TN, g0, lane, pv);
            else if (KSn == 2) stage_issue<2>(x, TN, g0, lane, pv);
            else               stage_issue<4>(x, TN, g0, lane, pv);
        }

        // 16 feature-tiles; transpose through Ep, flush dense every 4 tiles
        #pragma unroll
        for (int ct4 = 0; ct4 < 4; ++ct4) {
            #pragma unroll
            for (int c = 0; c < 4; ++c) {
                const int ct = ct4 * 4 + c;
                short8 wf[KS];
                if constexpr (PRE) {
                    #pragma unroll
                    for (int ks = 0; ks < KS; ++ks)
                        wf[ks] = wp[(((T * 16 + ct) * 4 + ks) * 4 + cgrp) * 16 + c16];
                } else {
                    const int dim = 16 << ((0x30123210u >> (4 * T)) & 0xf);
                    #pragma unroll
                    for (int ks = 0; ks < KS; ++ks) {
                        const int k = ks * 32 + cgrp * 8;
                        const float* wfp = W + ((size_t)T * FEAT + ct * 16 + c16) * MAXD + k;
                        f32x4 wa = *(const f32x4*)wfp;
                        f32x4 wb = *(const f32x4*)(wfp + 4);
                        #pragma unroll
                        for (int j = 0; j < 4; ++j) {
                            if (k + j     >= dim) wa[j] = 0.f;
                            if (k + 4 + j >= dim) wb[j] = 0.f;
                        }
                        wf[ks] = cvt8(wa, wb);
                    }
                }
                f32x4 acc = {0.f, 0.f, 0.f, 0.f};
                #pragma unroll
                for (int ks = 0; ks < KS; ++ks)
                    acc = __builtin_amdgcn_mfma_f32_16x16x32_bf16(a[ks], wf[ks], acc, 0, 0, 0);
                // D: row (graph) = cgrp*4 + r, col (feat) = ct*16 + c16 [m89]
                #pragma unroll
                for (int r = 0; r < 4; ++r)
                    ep[(cgrp * 4 + r) * ELDA + c * 16 + c16] = acc[r];
            }
            // flush: 16 graphs x 64 feats; 1KB dense per instr (8 full lines)
            #pragma unroll
            for (int fi = 0; fi < 4; ++fi) {
                const int row   = fi * 4 + (lane >> 4);
                const int coldw = (lane & 15) * 4;
                f32x4 v  = *(const f32x4*)&ep[row * ELDA + coldw];
                f32x4 b4 = *(const f32x4*)&bias_g[T * FEAT + ct4 * 64 + coldw];
                f32x4 res;
                #pragma unroll
                for (int r = 0; r < 4; ++r) res[r] = v[r] + b4[r];
                __builtin_nontemporal_store(res,
                    (f32x4*)&out[(((size_t)(g0 + row)) * NTYPES + T) * FEAT + ct4 * 64 + coldw]);
            }
        }

        // write prefetched rows into As (in-order DS pipe: after frag reads)
        if (i + 1 < NTYPES) {
            if (KSn == 1)      stage_write<1>(as_, lane, pv);
            else if (KSn == 2) stage_write<2>(as_, lane, pv);
            else               stage_write<4>(as_, lane, pv);
        }
    }
}

// 4 independent waves per block, 16 graphs each (100000 = 6250x16; surplus
// waves exit whole). Zero __syncthreads. Same executed schedule as R12; the
// only change is code size (3 loop bodies vs 8 unrolled -> fits I-cache).
template<bool PRE>
__global__ __launch_bounds__(256, 3)
void node_enc(const float* __restrict__ x, const short8* __restrict__ wp,
              const float* __restrict__ W, const float* __restrict__ bias_g,
              float* __restrict__ out)
{
    __shared__ __align__(16) unsigned short As[4][16 * ALDA];  // 17408 B
    __shared__ __align__(16) float          Ep[4][16 * ELDA];  // 17408 B
    const int tid  = threadIdx.x;
    const int lane = tid & 63;
    const int wave = tid >> 6;
    const int cgrp = lane >> 4;
    const int c16  = lane & 15;
    const int w    = blockIdx.x * 4 + wave;
    if (w >= N_GRAPHS / 16) return;   // whole-wave exit (last block only)
    const int g0   = w * 16;

    unsigned short* as_ = As[wave];
    float*          ep  = Ep[wave];

    // prologue: stage ORDER[0] = type 0 (KS=1)
    {
        f32x4 pv[2];
        stage_issue<1>(x, 0, g0, lane, pv);
        stage_write<1>(as_, lane, pv);
    }

    do_class<1, PRE>(0, 4, x, wp, W, bias_g, out, as_, ep, g0, lane, cgrp, c16);
    do_class<2, PRE>(4, 6, x, wp, W, bias_g, out, as_, ep, g0, lane, cgrp, c16);
    do_class<4, PRE>(6, 8, x, wp, W, bias_g, out, as_, ep, g0, lane, cgrp, c16);
}

extern "C" void kernel_launch(void* const* d_in, const int* in_sizes, int n_in,
                              void* d_out, int out_size, void* d_ws, size_t ws_size,
                              hipStream_t stream)
{
    const float* x = (const float*)d_in[0];
    const float* W = (const float*)d_in[1];
    const float* b = (const float*)d_in[2];
    float* out = (float*)d_out;

    const int grid = (N_GRAPHS / 16 + 3) / 4;                 // 1563
    const size_t wp_bytes = (size_t)32768 * sizeof(short8);   // 512 KB

    if (ws_size >= wp_bytes) {
        short8* wp = (short8*)d_ws;
        prepack_w<<<128, 256, 0, stream>>>(W, wp);
        node_enc<true><<<grid, 256, 0, stream>>>(x, wp, W, b, out);
    } else {
        node_enc<false><<<grid, 256, 0, stream>>>(x, nullptr, W, b, out);
    }
}

// Round 19
// 294.762 us; speedup vs baseline: 1.0511x; 1.0160x over previous
//
#include <hip/hip_runtime.h>

#define N_GRAPHS 100000
#define NTYPES 8
#define MAXD 128
#define FEAT 256
#define GPW 32      // graphs per wave (one 32x32 MFMA M-tile)
#define LDRF 68     // buf row stride in floats (272B); 32 rows = 8704B/wave
#define LDRS 136    // same stride in shorts

typedef __attribute__((ext_vector_type(8)))  short short8;
typedef __attribute__((ext_vector_type(4)))  float f32x4;
typedef __attribute__((ext_vector_type(16))) float f32x16;
typedef __attribute__((ext_vector_type(4)))  unsigned uint4v;

// dims {16,32,64,128,64,32,16,128}; KS16 = dim/16 (K-steps of 16)
constexpr int KS16N[NTYPES] = {1, 2, 4, 8, 4, 2, 1, 8};

__device__ __forceinline__ unsigned f2bf_u(float f) {
    unsigned u = __builtin_bit_cast(unsigned, f);
    return (u + 0x7fffu + ((u >> 16) & 1u)) >> 16;   // round-to-nearest-even
}
__device__ __forceinline__ unsigned cvt2(float lo, float hi) {
    return f2bf_u(lo) | (f2bf_u(hi) << 16);
}
__device__ __forceinline__ short8 cvt8(f32x4 a, f32x4 b) {
    uint4v u;
    u.x = cvt2(a.x, a.y); u.y = cvt2(a.z, a.w);
    u.z = cvt2(b.x, b.y); u.w = cvt2(b.z, b.w);
    return __builtin_bit_cast(short8, u);
}

// --- W -> bf16 32x32-B-fragment prepack. Entry (t, ct(32-feat tile), ks(K16
// step), half, c32): wp[(((t*8+ct)*8+ks)*2+half)*32+c32] = short8 of
// W[t][ct*32+c32][ks*16+half*8 .. +7], zero-masked at k >= dim. 512 KB.
__global__ __launch_bounds__(256)
void prepack_w32(const float* __restrict__ W, short8* __restrict__ wp)
{
    const int idx  = blockIdx.x * 256 + threadIdx.x;   // 32768
    const int c32  = idx & 31;
    const int half = (idx >> 5) & 1;
    const int ks   = (idx >> 6) & 7;
    const int ct   = (idx >> 9) & 7;
    const int t    = (idx >> 12) & 7;
    const int col  = ct * 32 + c32;
    const int k    = ks * 16 + half * 8;
    const int dim  = 16 << ((0x30123210u >> (4 * t)) & 0xf);
    const float* src = W + ((size_t)t * FEAT + col) * MAXD + k;
    f32x4 a = *(const f32x4*)src;
    f32x4 b = *(const f32x4*)(src + 4);
    #pragma unroll
    for (int j = 0; j < 4; ++j) {
        if (k + j     >= dim) a[j] = 0.f;
        if (k + 4 + j >= dim) b[j] = 0.f;
    }
    wp[idx] = cvt8(a, b);
}

// One type for one wave's 32 graphs, 32x32x16 MFMA. Barrier-free: buf is
// wave-private and serves As (staged x) then Ep (epilogue transpose); the
// per-wave DS pipe is in-order and A-frags are in regs before Ep clobbers.
// A operand: row(graph) = lane&31, k = ks*16 + (lane>>5)*8 + j.
// B operand: col(feat)  = lane&31, same k.   D: col = lane&31,
// row = (reg&3) + 8*(reg>>2) + 4*(lane>>5)   [m74/m101 verified].
template<int T, bool PRE>
__device__ __forceinline__ void do_type(const float* __restrict__ x,
                                        const short8* __restrict__ wp,
                                        const float* __restrict__ W,
                                        const float* __restrict__ bias_g,
                                        float* __restrict__ out,
                                        float* __restrict__ buf,
                                        int g0, int lane, int c32, int half)
{
    constexpr int KS = KS16N[T];

    // A fragments (then buf is free for Ep): float-typed reads, bit-cast
    short8 a[KS];
    #pragma unroll
    for (int ks = 0; ks < KS; ++ks) {
        f32x4 tmp = *(const f32x4*)&buf[c32 * LDRF + ks * 8 + half * 4];
        a[ks] = __builtin_bit_cast(short8, tmp);
    }

    // 4 pairs of 32-feat tiles; flush 64 feats x 32 graphs after each pair
    #pragma unroll
    for (int ct2 = 0; ct2 < 4; ++ct2) {
        #pragma unroll
        for (int cc = 0; cc < 2; ++cc) {
            const int ct = ct2 * 2 + cc;
            f32x16 acc = {0.f,0.f,0.f,0.f,0.f,0.f,0.f,0.f,
                          0.f,0.f,0.f,0.f,0.f,0.f,0.f,0.f};
            #pragma unroll
            for (int ks = 0; ks < KS; ++ks) {
                short8 wf;
                if constexpr (PRE) {
                    wf = wp[(((T * 8 + ct) * 8 + ks) * 2 + half) * 32 + c32];
                } else {
                    const int dim = 16 << ((0x30123210u >> (4 * T)) & 0xf);
                    const int k = ks * 16 + half * 8;
                    const float* wfp = W + ((size_t)T * FEAT + ct * 32 + c32) * MAXD + k;
                    f32x4 wa = *(const f32x4*)wfp;
                    f32x4 wb = *(const f32x4*)(wfp + 4);
                    #pragma unroll
                    for (int j = 0; j < 4; ++j) {
                        if (k + j     >= dim) wa[j] = 0.f;
                        if (k + 4 + j >= dim) wb[j] = 0.f;
                    }
                    wf = cvt8(wa, wb);
                }
                acc = __builtin_amdgcn_mfma_f32_32x32x16_bf16(a[ks], wf, acc, 0, 0, 0);
            }
            // D -> Ep: row = (r&3) + 8*(r>>2) + 4*half, col = cc*32 + c32
            #pragma unroll
            for (int r = 0; r < 16; ++r) {
                const int row = (r & 3) + 8 * (r >> 2) + 4 * half;
                buf[row * LDRF + cc * 32 + c32] = acc[r];
            }
        }
        // flush: 32 graphs x 64 feats; each instr = 4 rows x 256B (full lines)
        #pragma unroll
        for (int i = 0; i < 8; ++i) {
            const int row   = i * 4 + (lane >> 4);    // 0..31
            const int coldw = (lane & 15) * 4;
            f32x4 v  = *(const f32x4*)&buf[row * LDRF + coldw];
            f32x4 b4 = *(const f32x4*)&bias_g[T * FEAT + ct2 * 64 + coldw];
            f32x4 res;
            #pragma unroll
            for (int r = 0; r < 4; ++r) res[r] = v[r] + b4[r];
            __builtin_nontemporal_store(res,
                (f32x4*)&out[(((size_t)(g0 + row)) * NTYPES + T) * FEAT + ct2 * 64 + coldw]);
        }
    }

    // stage next type's x into buf (after last flush read; in-order DS pipe)
    if constexpr (T + 1 < NTYPES) {
        constexpr int KSn  = KS16N[T + 1];
        constexpr int SPRn = KSn * 2;           // 8-float segments per row
        #pragma unroll
        for (int p = 0; p < KSn; ++p) {         // 32 rows x SPRn / 64 lanes
            const int idx = p * 64 + lane;
            const int row = idx / SPRn, s8 = idx % SPRn;
            const float* rp = x + (((size_t)(g0 + row)) * NTYPES + (T + 1)) * MAXD + s8 * 8;
            f32x4 v0 = __builtin_nontemporal_load((const f32x4*)rp);
            f32x4 v1 = __builtin_nontemporal_load((const f32x4*)rp + 1);
            f32x4 cv = __builtin_bit_cast(f32x4, cvt8(v0, v1));
            *(f32x4*)&buf[row * LDRF + s8 * 4] = cv;
        }
        do_type<T + 1, PRE>(x, wp, W, bias_g, out, buf, g0, lane, c32, half);
    }
}

// 3125 wave-tiles of 32 graphs (100000 = 3125*32, zero masking); 782 blocks
// x 4 independent waves, zero __syncthreads. LDS = 4 x 8704B = 34.8KB ->
// 4 blocks/CU (16 waves/CU) at launch_bounds(256,4). The round's one lever:
// 32x32x16 MFMA halves wp L2 traffic (16->7.5 KB/graph) and MFMA count.
template<bool PRE>
__global__ __launch_bounds__(256, 4)
void node_enc(const float* __restrict__ x, const short8* __restrict__ wp,
              const float* __restrict__ W, const float* __restrict__ bias_g,
              float* __restrict__ out)
{
    __shared__ __align__(16) float Buf[4][GPW * LDRF];   // 4 x 8704 B
    const int tid  = threadIdx.x;
    const int lane = tid & 63;
    const int wave = tid >> 6;
    const int c32  = lane & 31;
    const int half = lane >> 5;
    const int w    = blockIdx.x * 4 + wave;
    if (w >= N_GRAPHS / GPW) return;   // 3 surplus waves exit (last block)
    const int g0   = w * GPW;

    float* buf = Buf[wave];
    // prologue: stage type 0 (dim 16 -> KS16=1: 32 rows x 2 segs, 1 pass)
    {
        const int row = lane >> 1, s8 = lane & 1;
        const float* rp = x + (((size_t)(g0 + row)) * NTYPES + 0) * MAXD + s8 * 8;
        f32x4 v0 = __builtin_nontemporal_load((const f32x4*)rp);
        f32x4 v1 = __builtin_nontemporal_load((const f32x4*)rp + 1);
        f32x4 cv = __builtin_bit_cast(f32x4, cvt8(v0, v1));
        *(f32x4*)&buf[row * LDRF + s8 * 4] = cv;
    }

    do_type<0, PRE>(x, wp, W, bias_g, out, buf, g0, lane, c32, half);
}

extern "C" void kernel_launch(void* const* d_in, const int* in_sizes, int n_in,
                              void* d_out, int out_size, void* d_ws, size_t ws_size,
                              hipStream_t stream)
{
    const float* x = (const float*)d_in[0];
    const float* W = (const float*)d_in[1];
    const float* b = (const float*)d_in[2];
    float* out = (float*)d_out;

    const int grid = (N_GRAPHS / GPW + 3) / 4;                // 782
    const size_t wp_bytes = (size_t)32768 * sizeof(short8);   // 512 KB

    if (ws_size >= wp_bytes) {
        short8* wp = (short8*)d_ws;
        prepack_w32<<<128, 256, 0, stream>>>(W, wp);
        node_enc<true><<<grid, 256, 0, stream>>>(x, wp, W, b, out);
    } else {
        node_enc<false><<<grid, 256, 0, stream>>>(x, nullptr, W, b, out);
    }
}